// Round 3
// baseline (1522.437 us; speedup 1.0000x reference)
//
#include <hip/hip_runtime.h>
#include <cstdint>
#include <cstddef>

// Problem constants (fixed by reference)
#define B_    4
#define S_    4096
#define DIN_  2048
#define DOUT_ 2048
#define R_    16
#define E_    12
// MULTIPLIER * SCALE == 1.0 — folded away.
// Decomposition: out = x @ W_org^T + (x @ W_down^T) @ combined[b]^T
// Single fused GEMM over M = B*S = 16384 (batch folded into rows).
// Round 6:
//   - REVERT: NT stores (write amplification 132->178 MB), lx fusion (L3 made
//     the xb re-read free; fusion only cut parallelism), read-ahead schedule
//     (neutral per counters).
//   - NEW: BK=32, 64 KiB LDS -> 2 blocks/CU. The ~50% per-phase drain stall
//     (vmcnt(0)+barrier with ONE resident block) is now hidden by the other
//     block's MFMA phase (m114 implicit overlap). Linear LDS [256][32]: with
//     64 B rows the bank index keeps the row parity term -> uniform
//     8 req/bank for 16x16 frag ds_read_b128, conflict-free with NO swizzle.
//   - All 512 blocks co-resident (256 CU x 2) -> no serial second round.

typedef __bf16 bf16x8  __attribute__((ext_vector_type(8)));
typedef float  floatx4  __attribute__((ext_vector_type(4)));

__device__ __forceinline__ unsigned int f2bf(float f) {
  unsigned int u = __builtin_bit_cast(unsigned int, f);
  u += 0x7fffu + ((u >> 16) & 1u);   // round-to-nearest-even
  return u >> 16;
}

__device__ __forceinline__ void async_copy16(const void* g, void* l) {
  __builtin_amdgcn_global_load_lds(
      (const __attribute__((address_space(1))) void*)g,
      (__attribute__((address_space(3))) void*)l,
      16, 0, 0);
}

// ---------------------------------------------------------------------------
// Kernel 1: x fp32 -> bf16, 8 elems/thread (16B stores).
// ---------------------------------------------------------------------------
__global__ __launch_bounds__(256) void cvt_x_kernel(const float* __restrict__ x,
                                                    unsigned short* __restrict__ xb) {
  size_t idx = ((size_t)blockIdx.x * 256 + threadIdx.x) * 8;
  float4 a = *(const float4*)(x + idx);
  float4 b = *(const float4*)(x + idx + 4);
  uint4 o;
  o.x = f2bf(a.x) | (f2bf(a.y) << 16);
  o.y = f2bf(a.z) | (f2bf(a.w) << 16);
  o.z = f2bf(b.x) | (f2bf(b.y) << 16);
  o.w = f2bf(b.z) | (f2bf(b.w) << 16);
  *(uint4*)(xb + idx) = o;
}

// ---------------------------------------------------------------------------
// Kernel 2 (fused prep): blocks [0,2048): W_org cvt; [2048,2064): W_down cvt;
// [2064,2576): combined[b,o,r] = sum_e gate[b,e]*W_up[e,o,r].
// ---------------------------------------------------------------------------
__global__ __launch_bounds__(256) void prep_misc_kernel(const float* __restrict__ W_org,
                                                        const float* __restrict__ W_down,
                                                        const float* __restrict__ gate,
                                                        const float* __restrict__ W_up,
                                                        unsigned short* __restrict__ worg,
                                                        unsigned short* __restrict__ wdb,
                                                        unsigned short* __restrict__ cmb) {
  const int bid = blockIdx.x;
  const int tid = threadIdx.x;
  if (bid < 2064) {
    const float* src;
    unsigned short* dst;
    size_t idx;
    if (bid < 2048) { src = W_org;  dst = worg; idx = ((size_t)bid * 256 + tid) * 8; }
    else            { src = W_down; dst = wdb;  idx = ((size_t)(bid - 2048) * 256 + tid) * 8; }
    float4 a = *(const float4*)(src + idx);
    float4 b = *(const float4*)(src + idx + 4);
    uint4 o;
    o.x = f2bf(a.x) | (f2bf(a.y) << 16);
    o.y = f2bf(a.z) | (f2bf(a.w) << 16);
    o.z = f2bf(b.x) | (f2bf(b.y) << 16);
    o.w = f2bf(b.z) | (f2bf(b.w) << 16);
    *(uint4*)(dst + idx) = o;
  } else {
    const int idx = (bid - 2064) * 256 + tid;    // over B*DOUT*R = 131072
    const int b   = idx >> 15;                   // DOUT*R = 32768
    const int orr = idx & 32767;
    float s = 0.f;
#pragma unroll
    for (int e = 0; e < E_; ++e)
      s += gate[b * E_ + e] * W_up[(size_t)e * DOUT_ * R_ + orr];
    cmb[idx] = (unsigned short)f2bf(s);
  }
}

// ---------------------------------------------------------------------------
// Kernel 3: lx = xb @ W_down^T  -> bf16  [16384 rows x 16]  (proven r2 version)
// ---------------------------------------------------------------------------
__global__ __launch_bounds__(256) void lx_kernel(const unsigned short* __restrict__ xb,
                                                 const unsigned short* __restrict__ wdb,
                                                 unsigned short* __restrict__ lxb) {
  const int tid  = threadIdx.x;
  const int lane = tid & 63;
  const int wave = tid >> 6;
  const int grp  = wave >> 1;        // 16-row group within block (0,1)
  const int kh   = wave & 1;         // K-half (0,1)
  const int q    = lane >> 4;
  const int mrow = lane & 15;
  const int row0 = blockIdx.x * 32 + grp * 16;

  floatx4 acc = {};
  const unsigned short* aptr = xb  + (size_t)(row0 + mrow) * DIN_ + kh * 1024 + q * 8;
  const unsigned short* bptr = wdb + (size_t)mrow * DIN_ + kh * 1024 + q * 8;
#pragma unroll 4
  for (int ks = 0; ks < 32; ++ks) {
    bf16x8 av = *(const bf16x8*)(aptr + ks * 32);
    bf16x8 bv = *(const bf16x8*)(bptr + ks * 32);
    acc = __builtin_amdgcn_mfma_f32_16x16x32_bf16(av, bv, acc, 0, 0, 0);
  }

  __shared__ float red[2][64 * 4];
  if (kh == 1) *(floatx4*)&red[grp][lane * 4] = acc;
  __syncthreads();
  if (kh == 0) {
    floatx4 o = *(const floatx4*)&red[grp][lane * 4];
    acc += o;
    // 16x16 C/D layout: col = lane&15 (= r), row = q*4 + reg
#pragma unroll
    for (int rg = 0; rg < 4; ++rg)
      lxb[(size_t)(row0 + q * 4 + rg) * R_ + mrow] = (unsigned short)f2bf(acc[rg]);
  }
}

// ---------------------------------------------------------------------------
// Kernel 4: fused NT GEMM  C = xb @ worg^T + lx @ cmb[batch]^T
// M = 16384 (batch = by>>4), N = 2048, K = 2048.
// 256x256 tile, BK=32, double-buffered 64 KiB LDS -> 2 blocks/CU.
// 2 phases per K-tile: {ds-reads | stage} -> barrier -> lgkm(0) ->
// setprio(1) 16 MFMA setprio(0) -> [vmcnt(0) at tile end] -> barrier.
// Fragment maps (16x16x32, verified m89/m91):
//   A/B frag: row = lane&15, k = (lane>>4)*8 + j
//   C/D     : col = lane&15, row = (lane>>4)*4 + reg
// LDS [256][32] bf16 LINEAR (64 B rows): bank = 16*(row&1) + 4*slot + word
// -> the 64-lane frag read lands uniformly 8 requests/bank = conflict-free.
// ---------------------------------------------------------------------------
__global__ __launch_bounds__(512, 4) void gemm256_kernel(const unsigned short* __restrict__ A,
                                                         const unsigned short* __restrict__ Bw,
                                                         const unsigned short* __restrict__ lx,
                                                         const unsigned short* __restrict__ cmb,
                                                         float* __restrict__ C) {
  constexpr int K = DIN_;
  __shared__ __align__(16) unsigned short lds[4 * 8192];    // 64 KiB
  unsigned short* ldsA0 = lds;                               // buf0 A (16 KiB)
  unsigned short* ldsB0 = lds + 8192;                        // buf0 B
  unsigned short* ldsA1 = lds + 16384;                       // buf1 A
  unsigned short* ldsB1 = lds + 24576;                       // buf1 B

  const int tid  = threadIdx.x;
  const int lane = tid & 63;
  const int wave = tid >> 6;
  const int wm   = wave >> 2;       // wave row (0..1) -> 128 rows
  const int wn   = wave & 3;        // wave col (0..3) -> 64 cols
  const int u    = lane & 15;       // frag row
  const int q    = lane >> 4;       // frag k-group / C row-group

  // XCD-aware bijective swizzle (nwg=512, 512%8==0): XCD x owns an 8x8 square.
  const int lin = blockIdx.x;
  const int swz = (lin & 7) * 64 + (lin >> 3);
  const int by  = swz >> 3;         // m-tile 0..63
  const int bx  = swz & 7;          // n-tile 0..7
  const int mBase = by * 256;
  const int nBase = bx * 256;
  const int batch = by >> 4;        // 16 m-tiles per batch; never straddles

  // LDS read bases (ushort units, 32/row): frag (h,mf2) rows wm*128+h*64+mf2*16+u
  const int aBase = (wm * 128 + u) * 32 + q * 8;
  const int bBase = (wn * 64 + u) * 32 + q * 8;

  floatx4 acc[8][4] = {};
  bf16x8 af[4], bfv[4];

  // Stage one 256x32 tile (16 KiB): 2 x global_load_lds dwordx4 per thread,
  // fully linear (dst = base + tid*16 within each 8 KiB chunk).
  auto stage = [&](const unsigned short* __restrict__ src, unsigned short* dstBase,
                   int rowBase, int k0) {
#pragma unroll
    for (int j = 0; j < 2; ++j) {
      const int p   = j * 8192 + tid * 16;     // byte offset in 16 KiB region
      const int row = p >> 6;                  // 64 B per row
      const int sl  = (p >> 4) & 3;            // 16B slot in row
      async_copy16(src + (size_t)(rowBase + row) * K + k0 + sl * 8,
                   (char*)dstBase + p);
    }
  };

#define PHASE(h, bufA_, bufB_, READB, STAGECODE, VMWAIT)                         \
  {                                                                              \
    _Pragma("unroll")                                                            \
    for (int mf2 = 0; mf2 < 4; ++mf2)                                            \
      af[mf2] = *(const bf16x8*)&bufA_[aBase + (h) * 2048 + mf2 * 512];          \
    if (READB) {                                                                 \
      _Pragma("unroll")                                                          \
      for (int nf = 0; nf < 4; ++nf)                                             \
        bfv[nf] = *(const bf16x8*)&bufB_[bBase + nf * 512];                      \
    }                                                                            \
    STAGECODE;                                                                   \
    __builtin_amdgcn_s_barrier();                                                \
    asm volatile("s_waitcnt lgkmcnt(0)" ::: "memory");                           \
    __builtin_amdgcn_s_setprio(1);                                               \
    _Pragma("unroll")                                                            \
    for (int mf2 = 0; mf2 < 4; ++mf2) {                                          \
      _Pragma("unroll")                                                          \
      for (int nf = 0; nf < 4; ++nf)                                             \
        acc[(h) * 4 + mf2][nf] = __builtin_amdgcn_mfma_f32_16x16x32_bf16(        \
            af[mf2], bfv[nf], acc[(h) * 4 + mf2][nf], 0, 0, 0);                  \
    }                                                                            \
    __builtin_amdgcn_s_setprio(0);                                               \
    VMWAIT;                                                                      \
    __builtin_amdgcn_s_barrier();                                                \
  }

  // ---- prologue: tile 0 -> buf0, full drain once ----
  stage(A,  ldsA0, mBase, 0);
  stage(Bw, ldsB0, nBase, 0);
  asm volatile("s_waitcnt vmcnt(0)" ::: "memory");
  __builtin_amdgcn_s_barrier();

  // Main loop: iteration computes K-tiles 2it (buf0) and 2it+1 (buf1).
  // Stage(t+1) issues in phase (t,h0) — target buffer's reads ended at the
  // previous tile's final barrier. vmcnt(0) at (t,h1) end: only tile t+1's
  // 4 loads are in flight, issued 1-2 phases earlier; with 2 blocks/CU the
  // other block's MFMA covers this drain.
  for (int it = 0; it < 32; ++it) {
    const int kB = it * 64 + 32;     // odd tile (buf1) k0
    const int kN = it * 64 + 64;     // next even tile (buf0) k0
    const bool more = (it < 31);
    PHASE(0, ldsA0, ldsB0, true,
          { stage(A, ldsA1, mBase, kB); stage(Bw, ldsB1, nBase, kB); }, )
    PHASE(1, ldsA0, ldsB0, false, ,
          asm volatile("s_waitcnt vmcnt(0)" ::: "memory"))
    PHASE(0, ldsA1, ldsB1, true,
          if (more) { stage(A, ldsA0, mBase, kN); stage(Bw, ldsB0, nBase, kN); }, )
    PHASE(1, ldsA1, ldsB1, false, ,
          asm volatile("s_waitcnt vmcnt(0)" ::: "memory"))
  }
#undef PHASE

  // ---- rank-16 LoRA epilogue: 16x16x32 with zero upper K-half (q>=2) ----
  {
    bf16x8 z = {};
    bf16x8 la[8], lb[4];
#pragma unroll
    for (int mf = 0; mf < 8; ++mf) {
      const size_t row = (size_t)(mBase + wm * 128 + mf * 16 + u);
      const unsigned short* p = lx + row * R_ + (q & 1) * 8;
      la[mf] = (q < 2) ? *(const bf16x8*)p : z;
    }
#pragma unroll
    for (int nf = 0; nf < 4; ++nf) {
      const size_t brow = (size_t)batch * DOUT_ + nBase + wn * 64 + nf * 16 + u;
      const unsigned short* p = cmb + brow * R_ + (q & 1) * 8;
      lb[nf] = (q < 2) ? *(const bf16x8*)p : z;
    }
#pragma unroll
    for (int mf = 0; mf < 8; ++mf)
#pragma unroll
      for (int nf = 0; nf < 4; ++nf)
        acc[mf][nf] = __builtin_amdgcn_mfma_f32_16x16x32_bf16(la[mf], lb[nf],
                                                              acc[mf][nf], 0, 0, 0);
  }

  // ---- store: col = nBase + wn*64 + nf*16 + u; row = ... + q*4 + rg ----
#pragma unroll
  for (int mf = 0; mf < 8; ++mf) {
    const int grow0 = mBase + wm * 128 + mf * 16 + q * 4;
#pragma unroll
    for (int nf = 0; nf < 4; ++nf) {
      const int gcol = nBase + wn * 64 + nf * 16 + u;
#pragma unroll
      for (int rg = 0; rg < 4; ++rg)
        C[(size_t)(grow0 + rg) * DOUT_ + gcol] = acc[mf][nf][rg];
    }
  }
}

// ---------------------------------------------------------------------------
extern "C" void kernel_launch(void* const* d_in, const int* in_sizes, int n_in,
                              void* d_out, int out_size, void* d_ws, size_t ws_size,
                              hipStream_t stream) {
  const float* x      = (const float*)d_in[0];
  const float* gate   = (const float*)d_in[1];
  const float* W_org  = (const float*)d_in[2];
  const float* W_down = (const float*)d_in[3];
  const float* W_up   = (const float*)d_in[4];
  float* out = (float*)d_out;

  // workspace layout (ushort elems):
  unsigned short* xb   = (unsigned short*)d_ws;             // 33,554,432
  unsigned short* worg = xb   + (size_t)B_ * S_ * DIN_;     //  4,194,304
  unsigned short* wdb  = worg + (size_t)DOUT_ * DIN_;       //     32,768
  unsigned short* lxb  = wdb  + (size_t)R_ * DIN_;          //    262,144
  unsigned short* cmb  = lxb  + (size_t)B_ * S_ * R_;       //    131,072

  // 1) x -> bf16
  cvt_x_kernel<<<(B_ * S_ * DIN_) / 2048, 256, 0, stream>>>(x, xb);

  // 2) fused prep: W_org cvt + W_down cvt + combined
  prep_misc_kernel<<<2576, 256, 0, stream>>>(W_org, W_down, gate, W_up, worg, wdb, cmb);

  // 3) lx = xb @ W_down^T  (bf16)
  lx_kernel<<<(B_ * S_) / 32, 256, 0, stream>>>(xb, wdb, lxb);

  // 4) out = xb @ worg^T + lx @ cmb[batch]^T  (fp32 out), BK=32 2-blocks/CU
  gemm256_kernel<<<512, 512, 0, stream>>>(xb, worg, lxb, cmb, out);
}

// Round 4
// 376.337 us; speedup vs baseline: 4.0454x; 4.0454x over previous
//
#include <hip/hip_runtime.h>
#include <cstdint>
#include <cstddef>

// Problem constants (fixed by reference)
#define B_    4
#define S_    4096
#define DIN_  2048
#define DOUT_ 2048
#define R_    16
#define E_    12
// MULTIPLIER * SCALE == 1.0 — folded away.
// Decomposition: out = x @ W_org^T + (x @ W_down^T) @ combined[b]^T
// Single fused GEMM over M = B*S = 16384 (batch folded into rows).
// Round 7 = R1 (proven 135.6 us) + counted vmcnt:
//   - R3 post-mortem: launch_bounds(512,4) capped regs at 128 -> acc spilled
//     to scratch (VGPR=64, FETCH 2.3 GB, MfmaUtil 4.5%). 256^2 tile REQUIRES
//     2 waves/SIMD; occupancy cannot exceed 1 block. Also linear [256][32]
//     LDS re-introduced 1.26e7 bank conflicts -> swizzle stays.
//   - NEW vs R1: stage(t+2) moves into tile t's LAST phase after lgkmcnt(0)
//     (buffer dead: all waves issued final reads before the phase barrier;
//     DMA return latency >> LDS queue service), then s_waitcnt vmcnt(8) --
//     waits only tile t+1's 8 loads (issued 4 phases ~1300 cyc earlier,
//     i.e. already landed) while t+2's 8 stay in flight across the barrier.
//     Removes R1's drain-0 stall on loads issued only 1 phase earlier
//     (m218: counted-vs-drain0 = +38..73% on this template).

typedef __bf16 bf16x8  __attribute__((ext_vector_type(8)));
typedef float  floatx4  __attribute__((ext_vector_type(4)));

__device__ __forceinline__ unsigned int f2bf(float f) {
  unsigned int u = __builtin_bit_cast(unsigned int, f);
  u += 0x7fffu + ((u >> 16) & 1u);   // round-to-nearest-even
  return u >> 16;
}

__device__ __forceinline__ void async_copy16(const void* g, void* l) {
  __builtin_amdgcn_global_load_lds(
      (const __attribute__((address_space(1))) void*)g,
      (__attribute__((address_space(3))) void*)l,
      16, 0, 0);
}

// ---------------------------------------------------------------------------
// Kernel 1: x fp32 -> bf16, 8 elems/thread (16B stores).
// ---------------------------------------------------------------------------
__global__ __launch_bounds__(256) void cvt_x_kernel(const float* __restrict__ x,
                                                    unsigned short* __restrict__ xb) {
  size_t idx = ((size_t)blockIdx.x * 256 + threadIdx.x) * 8;
  float4 a = *(const float4*)(x + idx);
  float4 b = *(const float4*)(x + idx + 4);
  uint4 o;
  o.x = f2bf(a.x) | (f2bf(a.y) << 16);
  o.y = f2bf(a.z) | (f2bf(a.w) << 16);
  o.z = f2bf(b.x) | (f2bf(b.y) << 16);
  o.w = f2bf(b.z) | (f2bf(b.w) << 16);
  *(uint4*)(xb + idx) = o;
}

// ---------------------------------------------------------------------------
// Kernel 2 (fused prep): blocks [0,2048): W_org cvt; [2048,2064): W_down cvt;
// [2064,2576): combined[b,o,r] = sum_e gate[b,e]*W_up[e,o,r].
// ---------------------------------------------------------------------------
__global__ __launch_bounds__(256) void prep_misc_kernel(const float* __restrict__ W_org,
                                                        const float* __restrict__ W_down,
                                                        const float* __restrict__ gate,
                                                        const float* __restrict__ W_up,
                                                        unsigned short* __restrict__ worg,
                                                        unsigned short* __restrict__ wdb,
                                                        unsigned short* __restrict__ cmb) {
  const int bid = blockIdx.x;
  const int tid = threadIdx.x;
  if (bid < 2064) {
    const float* src;
    unsigned short* dst;
    size_t idx;
    if (bid < 2048) { src = W_org;  dst = worg; idx = ((size_t)bid * 256 + tid) * 8; }
    else            { src = W_down; dst = wdb;  idx = ((size_t)(bid - 2048) * 256 + tid) * 8; }
    float4 a = *(const float4*)(src + idx);
    float4 b = *(const float4*)(src + idx + 4);
    uint4 o;
    o.x = f2bf(a.x) | (f2bf(a.y) << 16);
    o.y = f2bf(a.z) | (f2bf(a.w) << 16);
    o.z = f2bf(b.x) | (f2bf(b.y) << 16);
    o.w = f2bf(b.z) | (f2bf(b.w) << 16);
    *(uint4*)(dst + idx) = o;
  } else {
    const int idx = (bid - 2064) * 256 + tid;    // over B*DOUT*R = 131072
    const int b   = idx >> 15;                   // DOUT*R = 32768
    const int orr = idx & 32767;
    float s = 0.f;
#pragma unroll
    for (int e = 0; e < E_; ++e)
      s += gate[b * E_ + e] * W_up[(size_t)e * DOUT_ * R_ + orr];
    cmb[idx] = (unsigned short)f2bf(s);
  }
}

// ---------------------------------------------------------------------------
// Kernel 3: lx = xb @ W_down^T  -> bf16  [16384 rows x 16]  (proven r2 version)
// ---------------------------------------------------------------------------
__global__ __launch_bounds__(256) void lx_kernel(const unsigned short* __restrict__ xb,
                                                 const unsigned short* __restrict__ wdb,
                                                 unsigned short* __restrict__ lxb) {
  const int tid  = threadIdx.x;
  const int lane = tid & 63;
  const int wave = tid >> 6;
  const int grp  = wave >> 1;        // 16-row group within block (0,1)
  const int kh   = wave & 1;         // K-half (0,1)
  const int q    = lane >> 4;
  const int mrow = lane & 15;
  const int row0 = blockIdx.x * 32 + grp * 16;

  floatx4 acc = {};
  const unsigned short* aptr = xb  + (size_t)(row0 + mrow) * DIN_ + kh * 1024 + q * 8;
  const unsigned short* bptr = wdb + (size_t)mrow * DIN_ + kh * 1024 + q * 8;
#pragma unroll 4
  for (int ks = 0; ks < 32; ++ks) {
    bf16x8 av = *(const bf16x8*)(aptr + ks * 32);
    bf16x8 bv = *(const bf16x8*)(bptr + ks * 32);
    acc = __builtin_amdgcn_mfma_f32_16x16x32_bf16(av, bv, acc, 0, 0, 0);
  }

  __shared__ float red[2][64 * 4];
  if (kh == 1) *(floatx4*)&red[grp][lane * 4] = acc;
  __syncthreads();
  if (kh == 0) {
    floatx4 o = *(const floatx4*)&red[grp][lane * 4];
    acc += o;
    // 16x16 C/D layout: col = lane&15 (= r), row = q*4 + reg
#pragma unroll
    for (int rg = 0; rg < 4; ++rg)
      lxb[(size_t)(row0 + q * 4 + rg) * R_ + mrow] = (unsigned short)f2bf(acc[rg]);
  }
}

// ---------------------------------------------------------------------------
// Kernel 4: fused NT GEMM  C = xb @ worg^T + lx @ cmb[batch]^T
// M = 16384 (batch = by>>4), N = 2048, K = 2048.
// 256x256 tile, BK=64, 8 phases per 2 K-tiles, counted-vmcnt prefetch.
// Fragment maps (16x16x32, verified m89/m91):
//   A/B frag: row = lane&15, k = (lane>>4)*8 + j
//   C/D     : col = lane&15, row = (lane>>4)*4 + reg
// LDS tile [256][64] bf16, 16B-slot swizzle phys = s ^ (row&7), staged linear
// with pre-swizzled global source (both-sides rule).
// Tile t reads buf (t&1). Tile t's LAST phase: after lgkmcnt(0), stage tile
// t+2 into the SAME buffer, then vmcnt(8) = wait t+1's 8 loads (issued 4
// phases earlier) while t+2's 8 remain in flight across the barrier.
// ---------------------------------------------------------------------------
__global__ __launch_bounds__(512, 2) void gemm256_kernel(const unsigned short* __restrict__ A,
                                                         const unsigned short* __restrict__ Bw,
                                                         const unsigned short* __restrict__ lx,
                                                         const unsigned short* __restrict__ cmb,
                                                         float* __restrict__ C) {
  constexpr int K = DIN_;
  __shared__ __align__(16) unsigned short lds[4 * 16384];   // 128 KiB
  unsigned short* ldsA0 = lds;                               // buf0 A (32 KiB)
  unsigned short* ldsB0 = lds + 16384;                       // buf0 B
  unsigned short* ldsA1 = lds + 32768;                       // buf1 A
  unsigned short* ldsB1 = lds + 49152;                       // buf1 B

  const int tid  = threadIdx.x;
  const int lane = tid & 63;
  const int wave = tid >> 6;
  const int wm   = wave >> 2;       // wave row (0..1) -> 128 rows
  const int wn   = wave & 3;        // wave col (0..3) -> 64 cols
  const int u    = lane & 15;       // frag row
  const int q    = lane >> 4;       // frag k-group / C row-group

  // XCD-aware bijective swizzle (nwg=512, 512%8==0): XCD x owns an 8x8 square.
  const int lin = blockIdx.x;
  const int swz = (lin & 7) * 64 + (lin >> 3);
  const int by  = swz >> 3;         // m-tile 0..63
  const int bx  = swz & 7;          // n-tile 0..7
  const int mBase = by * 256;
  const int nBase = bx * 256;
  const int batch = by >> 4;        // 16 m-tiles per batch; never straddles

  const int aBase = (wm * 128 + u) * 64;
  const int bBase = (wn * 64 + u) * 64;
  const int swzK0 = (q ^ (u & 7)) << 3;          // kc=0: slot q
  const int swzK1 = ((4 + q) ^ (u & 7)) << 3;    // kc=1: slot 4+q

  floatx4 acc[8][4] = {};
  bf16x8 af[4], bfv[4];

  // Stage one full 256x64 tile (32 KiB): 4 x global_load_lds dwordx4 per
  // thread; LDS dst linear, global source pre-swizzled (involution).
  auto stage = [&](const unsigned short* __restrict__ src, unsigned short* dstBase,
                   int rowBase, int k0) {
#pragma unroll
    for (int j = 0; j < 4; ++j) {
      const int p   = j * 8192 + tid * 16;     // byte offset in 32 KiB region
      const int row = p >> 7;                  // 128 B per row
      const int sp  = (p >> 4) & 7;            // phys 16B slot
      const int ss  = sp ^ (row & 7);          // source slot
      async_copy16(src + (size_t)(rowBase + row) * K + k0 + ss * 8,
                   (char*)dstBase + p);
    }
  };

  // Phase: reads -> barrier -> lgkm(0) -> [STAGE] -> setprio/16 MFMA -> [VMW]
  // -> barrier.  STAGE sits after lgkm(0): this phase's reads of the target
  // buffer have completed for this wave; all other waves issued theirs before
  // the phase barrier and DMA return latency (>=500cy) >> LDS service.
#define PHASE(h, bufA_, bufB_, READB, SWZ, STAGECODE, VMWAIT)                    \
  {                                                                              \
    _Pragma("unroll")                                                            \
    for (int mf2 = 0; mf2 < 4; ++mf2)                                            \
      af[mf2] = *(const bf16x8*)&bufA_[aBase + ((h) * 4 + mf2) * 1024 + (SWZ)];  \
    if (READB) {                                                                 \
      _Pragma("unroll")                                                          \
      for (int nf = 0; nf < 4; ++nf)                                             \
        bfv[nf] = *(const bf16x8*)&bufB_[bBase + nf * 1024 + (SWZ)];             \
    }                                                                            \
    __builtin_amdgcn_s_barrier();                                                \
    asm volatile("s_waitcnt lgkmcnt(0)" ::: "memory");                           \
    STAGECODE;                                                                   \
    __builtin_amdgcn_s_setprio(1);                                               \
    _Pragma("unroll")                                                            \
    for (int mf2 = 0; mf2 < 4; ++mf2) {                                          \
      _Pragma("unroll")                                                          \
      for (int nf = 0; nf < 4; ++nf)                                             \
        acc[(h) * 4 + mf2][nf] = __builtin_amdgcn_mfma_f32_16x16x32_bf16(        \
            af[mf2], bfv[nf], acc[(h) * 4 + mf2][nf], 0, 0, 0);                  \
    }                                                                            \
    __builtin_amdgcn_s_setprio(0);                                               \
    VMWAIT;                                                                      \
    __builtin_amdgcn_s_barrier();                                                \
  }

  // ---- prologue: tiles 0,1 in flight; wait only tile 0 (vmcnt(8)) ----
  stage(A,  ldsA0, mBase, 0);
  stage(Bw, ldsB0, nBase, 0);
  stage(A,  ldsA1, mBase, 64);
  stage(Bw, ldsB1, nBase, 64);
  asm volatile("s_waitcnt vmcnt(8)" ::: "memory");
  __builtin_amdgcn_s_barrier();

  for (int it = 0; it < 16; ++it) {
    const int kN0 = it * 128 + 128;  // tile 2it+2 -> buf0
    const int kN1 = it * 128 + 192;  // tile 2it+3 -> buf1
    const bool more = (it < 15);
    // ---- tile 2it (buf0) ----
    PHASE(0, ldsA0, ldsB0, true,  swzK0, , )
    PHASE(1, ldsA0, ldsB0, false, swzK0, , )
    PHASE(0, ldsA0, ldsB0, true,  swzK1, , )
    PHASE(1, ldsA0, ldsB0, false, swzK1,
          if (more) { stage(A, ldsA0, mBase, kN0); stage(Bw, ldsB0, nBase, kN0); },
          if (more) { asm volatile("s_waitcnt vmcnt(8)" ::: "memory"); }
          else      { asm volatile("s_waitcnt vmcnt(0)" ::: "memory"); })
    // ---- tile 2it+1 (buf1) ----
    PHASE(0, ldsA1, ldsB1, true,  swzK0, , )
    PHASE(1, ldsA1, ldsB1, false, swzK0, , )
    PHASE(0, ldsA1, ldsB1, true,  swzK1, , )
    PHASE(1, ldsA1, ldsB1, false, swzK1,
          if (more) { stage(A, ldsA1, mBase, kN1); stage(Bw, ldsB1, nBase, kN1); },
          if (more) { asm volatile("s_waitcnt vmcnt(8)" ::: "memory"); })
  }
#undef PHASE

  // ---- rank-16 LoRA epilogue: 16x16x32 with zero upper K-half (q>=2) ----
  {
    bf16x8 z = {};
    bf16x8 la[8], lb[4];
#pragma unroll
    for (int mf = 0; mf < 8; ++mf) {
      const size_t row = (size_t)(mBase + wm * 128 + mf * 16 + u);
      const unsigned short* p = lx + row * R_ + (q & 1) * 8;
      la[mf] = (q < 2) ? *(const bf16x8*)p : z;
    }
#pragma unroll
    for (int nf = 0; nf < 4; ++nf) {
      const size_t brow = (size_t)batch * DOUT_ + nBase + wn * 64 + nf * 16 + u;
      const unsigned short* p = cmb + brow * R_ + (q & 1) * 8;
      lb[nf] = (q < 2) ? *(const bf16x8*)p : z;
    }
#pragma unroll
    for (int mf = 0; mf < 8; ++mf)
#pragma unroll
      for (int nf = 0; nf < 4; ++nf)
        acc[mf][nf] = __builtin_amdgcn_mfma_f32_16x16x32_bf16(la[mf], lb[nf],
                                                              acc[mf][nf], 0, 0, 0);
  }

  // ---- store: col = nBase + wn*64 + nf*16 + u; row = ... + q*4 + rg ----
#pragma unroll
  for (int mf = 0; mf < 8; ++mf) {
    const int grow0 = mBase + wm * 128 + mf * 16 + q * 4;
#pragma unroll
    for (int nf = 0; nf < 4; ++nf) {
      const int gcol = nBase + wn * 64 + nf * 16 + u;
#pragma unroll
      for (int rg = 0; rg < 4; ++rg)
        C[(size_t)(grow0 + rg) * DOUT_ + gcol] = acc[mf][nf][rg];
    }
  }
}

// ---------------------------------------------------------------------------
extern "C" void kernel_launch(void* const* d_in, const int* in_sizes, int n_in,
                              void* d_out, int out_size, void* d_ws, size_t ws_size,
                              hipStream_t stream) {
  const float* x      = (const float*)d_in[0];
  const float* gate   = (const float*)d_in[1];
  const float* W_org  = (const float*)d_in[2];
  const float* W_down = (const float*)d_in[3];
  const float* W_up   = (const float*)d_in[4];
  float* out = (float*)d_out;

  // workspace layout (ushort elems):
  unsigned short* xb   = (unsigned short*)d_ws;             // 33,554,432
  unsigned short* worg = xb   + (size_t)B_ * S_ * DIN_;     //  4,194,304
  unsigned short* wdb  = worg + (size_t)DOUT_ * DIN_;       //     32,768
  unsigned short* lxb  = wdb  + (size_t)R_ * DIN_;          //    262,144
  unsigned short* cmb  = lxb  + (size_t)B_ * S_ * R_;       //    131,072

  // 1) x -> bf16
  cvt_x_kernel<<<(B_ * S_ * DIN_) / 2048, 256, 0, stream>>>(x, xb);

  // 2) fused prep: W_org cvt + W_down cvt + combined
  prep_misc_kernel<<<2576, 256, 0, stream>>>(W_org, W_down, gate, W_up, worg, wdb, cmb);

  // 3) lx = xb @ W_down^T  (bf16)
  lx_kernel<<<(B_ * S_) / 32, 256, 0, stream>>>(xb, wdb, lxb);

  // 4) out = xb @ worg^T + lx @ cmb[batch]^T  (fp32 out), counted-vmcnt
  gemm256_kernel<<<512, 512, 0, stream>>>(xb, worg, lxb, cmb, out);
}